// Round 1
// baseline (567.979 us; speedup 1.0000x reference)
//
#include <hip/hip_runtime.h>

#define D 128

// ---------------- CSR build ----------------

__global__ void hist_k(const int* __restrict__ tgt, int* __restrict__ cnt, int E) {
    int i = blockIdx.x * blockDim.x + threadIdx.x;
    if (i < E) atomicAdd(&cnt[tgt[i]], 1);
}

__global__ void scan_k(const int* __restrict__ cnt, int* __restrict__ row_ptr, int n) {
    __shared__ int lds[1024];
    int t = threadIdx.x;
    int seg = (n + 1023) / 1024;
    int lo = t * seg, hi = lo + seg;
    if (hi > n) hi = n;
    if (lo > n) lo = n;
    int s = 0;
    for (int i = lo; i < hi; ++i) s += cnt[i];
    lds[t] = s;
    __syncthreads();
    for (int off = 1; off < 1024; off <<= 1) {
        int v = (t >= off) ? lds[t - off] : 0;
        __syncthreads();
        lds[t] += v;
        __syncthreads();
    }
    int excl = lds[t] - s;
    for (int i = lo; i < hi; ++i) { row_ptr[i] = excl; excl += cnt[i]; }
    if (t == 1023) row_ptr[n] = lds[1023];
}

__global__ void fill_k(const int* __restrict__ src, const int* __restrict__ tgt,
                       const int* __restrict__ row_ptr, int* __restrict__ cur,
                       int* __restrict__ srcs, int E) {
    int i = blockIdx.x * blockDim.x + threadIdx.x;
    if (i < E) {
        int tg = tgt[i];
        int p = row_ptr[tg] + atomicAdd(&cur[tg], 1);
        srcs[p] = src[i];
    }
}

// ---------------- mean aggregation (CSR gather) ----------------
// one block (64 threads) per node; each lane owns 2 features (float2)

__global__ void aggr_k(const float* __restrict__ X, const int* __restrict__ srcs,
                       const int* __restrict__ row_ptr, float* __restrict__ aggr) {
    int node = blockIdx.x;
    int t = threadIdx.x;  // 0..63
    int lo = row_ptr[node], hi = row_ptr[node + 1];
    float ax = 0.f, ay = 0.f;
#pragma unroll 4
    for (int e = lo; e < hi; ++e) {
        int s = srcs[e];
        float2 v = *reinterpret_cast<const float2*>(&X[(size_t)s * D + t * 2]);
        ax += v.x;
        ay += v.y;
    }
    float inv = 1.0f / fmaxf((float)(hi - lo), 1.0f);
    float2 r;
    r.x = ax * inv;
    r.y = ay * inv;
    *reinterpret_cast<float2*>(&aggr[(size_t)node * D + t * 2]) = r;
}

// ---------------- fused concat-GEMM + bias + relu ----------------
// out[n][j] = relu( sum_k X[n][k] W[k][j] + sum_k A[n][k] W[128+k][j] + b[j] )
// block = 256 threads; thread = (jg = t&31 -> 4 outputs, ng = t>>5 -> 4 nodes)
// block tile: 32 nodes x 128 outputs. W read through L1 (128 KB, shared by CU).

__global__ __launch_bounds__(256) void gemm_k(
    const float* __restrict__ X, const float* __restrict__ A,
    const float* __restrict__ W, const float* __restrict__ bias,
    float* __restrict__ out, int n) {
    int jg = threadIdx.x & 31;
    int ng = threadIdx.x >> 5;
    int j0 = jg * 4;
    int node0 = blockIdx.x * 32 + ng * 4;
    float acc[4][4] = {{0.f}};
    for (int half = 0; half < 2; ++half) {
        const float* __restrict__ R = half ? A : X;
        const float* __restrict__ Wh = W + half * 128 * 128;
        for (int k = 0; k < 128; k += 4) {
            float4 w0 = *reinterpret_cast<const float4*>(&Wh[(k + 0) * 128 + j0]);
            float4 w1 = *reinterpret_cast<const float4*>(&Wh[(k + 1) * 128 + j0]);
            float4 w2 = *reinterpret_cast<const float4*>(&Wh[(k + 2) * 128 + j0]);
            float4 w3 = *reinterpret_cast<const float4*>(&Wh[(k + 3) * 128 + j0]);
#pragma unroll
            for (int ni = 0; ni < 4; ++ni) {
                int node = node0 + ni;
                if (node > n - 1) node = n - 1;  // clamp (last block only)
                float4 xv = *reinterpret_cast<const float4*>(&R[(size_t)node * D + k]);
                acc[ni][0] += xv.x * w0.x + xv.y * w1.x + xv.z * w2.x + xv.w * w3.x;
                acc[ni][1] += xv.x * w0.y + xv.y * w1.y + xv.z * w2.y + xv.w * w3.y;
                acc[ni][2] += xv.x * w0.z + xv.y * w1.z + xv.z * w2.z + xv.w * w3.z;
                acc[ni][3] += xv.x * w0.w + xv.y * w1.w + xv.z * w2.w + xv.w * w3.w;
            }
        }
    }
    float4 b4 = *reinterpret_cast<const float4*>(&bias[j0]);
    // barrier: for the in-place layer-2 call, guarantee all reads of this
    // block's rows (incl. clamped tail reads) complete before any store.
    __syncthreads();
#pragma unroll
    for (int ni = 0; ni < 4; ++ni) {
        int node = node0 + ni;
        if (node < n) {
            float4 r;
            r.x = fmaxf(acc[ni][0] + b4.x, 0.f);
            r.y = fmaxf(acc[ni][1] + b4.y, 0.f);
            r.z = fmaxf(acc[ni][2] + b4.z, 0.f);
            r.w = fmaxf(acc[ni][3] + b4.w, 0.f);
            *reinterpret_cast<float4*>(&out[(size_t)node * D + j0]) = r;
        }
    }
}

extern "C" void kernel_launch(void* const* d_in, const int* in_sizes, int n_in,
                              void* d_out, int out_size, void* d_ws, size_t ws_size,
                              hipStream_t stream) {
    const float* x  = (const float*)d_in[0];
    const int*   ei = (const int*)d_in[1];
    const float* W1 = (const float*)d_in[2];
    const float* b1 = (const float*)d_in[3];
    const float* W2 = (const float*)d_in[4];
    const float* b2 = (const float*)d_in[5];
    float* out = (float*)d_out;

    const int N = in_sizes[0] / D;  // 50000
    const int E = in_sizes[1] / 2;  // 800000
    const int* src = ei;
    const int* tgt = ei + E;

    char* w = (char*)d_ws;
    int* row_ptr = (int*)w;  w += (((size_t)(N + 1) * 4 + 255) / 256) * 256;
    int* cnt     = (int*)w;  w += (((size_t)N * 4 + 255) / 256) * 256;
    int* srcs    = (int*)w;  w += (((size_t)E * 4 + 255) / 256) * 256;
    float* aggr  = (float*)w;  // N*D floats (25.6 MB)

    // ---- CSR build (shared by both layers) ----
    hipMemsetAsync(cnt, 0, (size_t)N * sizeof(int), stream);
    hist_k<<<(E + 255) / 256, 256, 0, stream>>>(tgt, cnt, E);
    scan_k<<<1, 1024, 0, stream>>>(cnt, row_ptr, N);
    hipMemsetAsync(cnt, 0, (size_t)N * sizeof(int), stream);
    fill_k<<<(E + 255) / 256, 256, 0, stream>>>(src, tgt, row_ptr, cnt, srcs, E);

    // ---- layer 1 ----
    aggr_k<<<N, 64, 0, stream>>>(x, srcs, row_ptr, aggr);
    gemm_k<<<(N + 31) / 32, 256, 0, stream>>>(x, aggr, W1, b1, out, N);

    // ---- layer 2 (h1 lives in d_out; gemm is safely in-place) ----
    aggr_k<<<N, 64, 0, stream>>>(out, srcs, row_ptr, aggr);
    gemm_k<<<(N + 31) / 32, 256, 0, stream>>>(out, aggr, W2, b2, out, N);
}